// Round 5
// baseline (1213.185 us; speedup 1.0000x reference)
//
#include <hip/hip_runtime.h>
#include <math.h>

#define N_NODES 50000
#define N_EDGES 800000
#define ETOT    850000   // N_EDGES + N_NODES self loops

static __device__ __forceinline__ float leaky(float v){ return v > 0.f ? v : 0.2f*v; }

// ---------------------------------------------------------------- CSR build

__global__ void zero_int_kernel(int* __restrict__ p, int n){
  int i = blockIdx.x*blockDim.x + threadIdx.x;
  if (i < n) p[i] = 0;
}

__global__ void hist_kernel(const int* __restrict__ ei, int* __restrict__ deg){
  int i = blockIdx.x*blockDim.x + threadIdx.x;
  if (i < ETOT){
    int d = (i < N_EDGES) ? ei[N_EDGES + i] : (i - N_EDGES);
    atomicAdd(&deg[d], 1);
  }
}

__global__ void scan1_kernel(const int* __restrict__ deg, int* __restrict__ incl,
                             int* __restrict__ bsum, int n){
  __shared__ int sm[1024];
  int i = blockIdx.x*1024 + threadIdx.x;
  int v = (i < n) ? deg[i] : 0;
  sm[threadIdx.x] = v;
  __syncthreads();
  for (int off = 1; off < 1024; off <<= 1){
    int t = (threadIdx.x >= off) ? sm[threadIdx.x - off] : 0;
    __syncthreads();
    sm[threadIdx.x] += t;
    __syncthreads();
  }
  if (i < n) incl[i] = sm[threadIdx.x];
  if (threadIdx.x == 1023) bsum[blockIdx.x] = sm[1023];
}

__global__ void scan2_kernel(int* __restrict__ bsum, int nb){
  if (threadIdx.x == 0 && blockIdx.x == 0){
    int acc = 0;
    for (int b = 0; b < nb; ++b){ int v = bsum[b]; bsum[b] = acc; acc += v; }
  }
}

__global__ void scan3_kernel(const int* __restrict__ incl, const int* __restrict__ deg,
                             const int* __restrict__ bsum, int* __restrict__ rowptr,
                             int* __restrict__ next, int n){
  int i = blockIdx.x*blockDim.x + threadIdx.x;
  if (i < n){
    int v = incl[i] - deg[i] + bsum[i >> 10];
    rowptr[i] = v;
    next[i]   = v;
  }
  if (i == n) rowptr[n] = ETOT;
}

__global__ void fill_kernel(const int* __restrict__ ei, int* __restrict__ next,
                            int* __restrict__ col){
  int i = blockIdx.x*blockDim.x + threadIdx.x;
  if (i < ETOT){
    int s, d;
    if (i < N_EDGES){ s = ei[i]; d = ei[N_EDGES + i]; }
    else            { s = i - N_EDGES; d = s; }
    int pos = atomicAdd(&next[d], 1);
    col[pos] = s;
  }
}

// ---------------------------------------------------------------- GEMM v2 (fp32, 8x8 thread tile)
// Y[M,C] = X[M,K] @ W[K,C], optional fused row-dots os = Y.a_s, od = Y.a_d.
// 256 threads = TXC col-threads x TYC row-threads; thread tile 8 rows x 8 cols
// (cols split: tx*4..+3 and C/2+tx*4..+3 so W reads are 256B-contiguous b128).
// X tile stored k-major (transposed) in LDS so X reads are b128 broadcasts.

template<int K, int C, bool DOT>
__launch_bounds__(256, 4)
__global__ void gemm2_kernel(const float* __restrict__ X, const float* __restrict__ W,
                             float* __restrict__ Y,
                             const float* __restrict__ a_s, const float* __restrict__ a_d,
                             float* __restrict__ os, float* __restrict__ od, int M)
{
  constexpr int TXC = C / 8;          // 16 (C=128) or 32 (C=256)
  constexpr int TYC = 256 / TXC;      // 16 or 8
  constexpr int TM  = TYC * 8;        // 128 or 64
  constexpr int KT  = 32;
  constexpr int HC  = C / 2;
  constexpr int F4  = KT / 4;         // 8

  __shared__ float Xt[KT][TM + 4];    // k-major; +4 keeps rows 16B-aligned, shifts banks
  __shared__ float Ws[KT][C];

  const int t  = threadIdx.x;
  const int tx = t % TXC;
  const int ty = t / TXC;
  const int r0 = blockIdx.x * TM;

  float acc[8][8];
  #pragma unroll
  for (int r = 0; r < 8; ++r)
    #pragma unroll
    for (int c = 0; c < 8; ++c) acc[r][c] = 0.f;

  for (int kt = 0; kt < K; kt += KT){
    // stage W tile (linear copy, KT rows of C floats)
    {
      const float4* wsrc = (const float4*)(W + (size_t)kt * C);
      float4* wdst = (float4*)(&Ws[0][0]);
      #pragma unroll
      for (int i = t; i < KT * C / 4; i += 256) wdst[i] = wsrc[i];
    }
    // stage X tile transposed: read float4 along k, scatter to k-major rows
    #pragma unroll
    for (int i = t; i < TM * F4; i += 256){
      int row = i / F4;
      int fq  = i % F4;
      float4 v = make_float4(0.f, 0.f, 0.f, 0.f);
      int gr = r0 + row;
      if (gr < M) v = *(const float4*)(X + (size_t)gr * K + kt + fq * 4);
      Xt[fq*4+0][row] = v.x; Xt[fq*4+1][row] = v.y;
      Xt[fq*4+2][row] = v.z; Xt[fq*4+3][row] = v.w;
    }
    __syncthreads();

    #pragma unroll
    for (int k = 0; k < KT; ++k){
      float xr[8], wc[8];
      *(float4*)&xr[0] = *(const float4*)&Xt[k][ty*8];
      *(float4*)&xr[4] = *(const float4*)&Xt[k][ty*8 + 4];
      *(float4*)&wc[0] = *(const float4*)&Ws[k][tx*4];
      *(float4*)&wc[4] = *(const float4*)&Ws[k][HC + tx*4];
      #pragma unroll
      for (int r = 0; r < 8; ++r)
        #pragma unroll
        for (int c = 0; c < 8; ++c)
          acc[r][c] += xr[r] * wc[c];
    }
    __syncthreads();
  }

  #pragma unroll
  for (int r = 0; r < 8; ++r){
    int row = r0 + ty*8 + r;
    if (row < M){
      *(float4*)(Y + (size_t)row * C + tx*4)      = *(float4*)&acc[r][0];
      *(float4*)(Y + (size_t)row * C + HC + tx*4) = *(float4*)&acc[r][4];
    }
  }

  if constexpr (DOT){
    float4 as0 = *(const float4*)(a_s + tx*4);
    float4 as1 = *(const float4*)(a_s + HC + tx*4);
    float4 ad0 = *(const float4*)(a_d + tx*4);
    float4 ad1 = *(const float4*)(a_d + HC + tx*4);
    #pragma unroll
    for (int r = 0; r < 8; ++r){
      float ps = acc[r][0]*as0.x + acc[r][1]*as0.y + acc[r][2]*as0.z + acc[r][3]*as0.w
               + acc[r][4]*as1.x + acc[r][5]*as1.y + acc[r][6]*as1.z + acc[r][7]*as1.w;
      float pd = acc[r][0]*ad0.x + acc[r][1]*ad0.y + acc[r][2]*ad0.z + acc[r][3]*ad0.w
               + acc[r][4]*ad1.x + acc[r][5]*ad1.y + acc[r][6]*ad1.z + acc[r][7]*ad1.w;
      #pragma unroll
      for (int off = TXC/2; off; off >>= 1){
        ps += __shfl_xor(ps, off);
        pd += __shfl_xor(pd, off);
      }
      int row = r0 + ty*8 + r;
      if (tx == 0 && row < M){ os[row] = ps; od[row] = pd; }
    }
  }
}

// ---------------------------------------------------------------- edge-softmax aggregation
// one wave per destination node; CSR over incoming edges; message loop unrolled x4.

template<int C, bool RELU>
__global__ void agg_kernel(const float* __restrict__ h, const float* __restrict__ as_,
                           const float* __restrict__ ad_, const int* __restrict__ rowptr,
                           const int* __restrict__ col, float* __restrict__ out, int n){
  int d    = (blockIdx.x * blockDim.x + threadIdx.x) >> 6;
  int lane = threadIdx.x & 63;
  if (d >= n) return;
  int beg = rowptr[d], end = rowptr[d+1];
  float add = ad_[d];

  float m = -INFINITY;
  for (int e = beg + lane; e < end; e += 64)
    m = fmaxf(m, leaky(as_[col[e]] + add));
  #pragma unroll
  for (int off = 32; off; off >>= 1) m = fmaxf(m, __shfl_xor(m, off));

  float ssum = 0.f;
  for (int e = beg + lane; e < end; e += 64)
    ssum += __expf(leaky(as_[col[e]] + add) - m);
  #pragma unroll
  for (int off = 32; off; off >>= 1) ssum += __shfl_xor(ssum, off);
  float inv = 1.f / (ssum + 1e-16f);

  const int last = end - 1;

  if constexpr (C == 128){
    float ax0=0.f,ay0=0.f, ax1=0.f,ay1=0.f, ax2=0.f,ay2=0.f, ax3=0.f,ay3=0.f;
    for (int e = beg; e < end; e += 4){
      int e1 = e+1 <= last ? e+1 : last;
      int e2 = e+2 <= last ? e+2 : last;
      int e3 = e+3 <= last ? e+3 : last;
      int s0 = col[e], s1 = col[e1], s2 = col[e2], s3 = col[e3];
      float w0 = __expf(leaky(as_[s0] + add) - m);
      float w1 = (e+1 <= last) ? __expf(leaky(as_[s1] + add) - m) : 0.f;
      float w2 = (e+2 <= last) ? __expf(leaky(as_[s2] + add) - m) : 0.f;
      float w3 = (e+3 <= last) ? __expf(leaky(as_[s3] + add) - m) : 0.f;
      float2 h0 = *(const float2*)(h + (size_t)s0 * C + lane*2);
      float2 h1 = *(const float2*)(h + (size_t)s1 * C + lane*2);
      float2 h2 = *(const float2*)(h + (size_t)s2 * C + lane*2);
      float2 h3 = *(const float2*)(h + (size_t)s3 * C + lane*2);
      ax0 += w0*h0.x; ay0 += w0*h0.y;
      ax1 += w1*h1.x; ay1 += w1*h1.y;
      ax2 += w2*h2.x; ay2 += w2*h2.y;
      ax3 += w3*h3.x; ay3 += w3*h3.y;
    }
    float ax = ((ax0+ax1)+(ax2+ax3)) * inv;
    float ay = ((ay0+ay1)+(ay2+ay3)) * inv;
    if (RELU){ ax = fmaxf(ax, 0.f); ay = fmaxf(ay, 0.f); }
    float2 o; o.x = ax; o.y = ay;
    *(float2*)(out + (size_t)d * C + lane*2) = o;
  } else {
    float a0[4]={0,0,0,0}, a1[4]={0,0,0,0}, a2[4]={0,0,0,0}, a3[4]={0,0,0,0};
    for (int e = beg; e < end; e += 4){
      int e1 = e+1 <= last ? e+1 : last;
      int e2 = e+2 <= last ? e+2 : last;
      int e3 = e+3 <= last ? e+3 : last;
      int s0 = col[e], s1 = col[e1], s2 = col[e2], s3 = col[e3];
      float w0 = __expf(leaky(as_[s0] + add) - m);
      float w1 = (e+1 <= last) ? __expf(leaky(as_[s1] + add) - m) : 0.f;
      float w2 = (e+2 <= last) ? __expf(leaky(as_[s2] + add) - m) : 0.f;
      float w3 = (e+3 <= last) ? __expf(leaky(as_[s3] + add) - m) : 0.f;
      float4 h0 = *(const float4*)(h + (size_t)s0 * C + lane*4);
      float4 h1 = *(const float4*)(h + (size_t)s1 * C + lane*4);
      float4 h2 = *(const float4*)(h + (size_t)s2 * C + lane*4);
      float4 h3 = *(const float4*)(h + (size_t)s3 * C + lane*4);
      a0[0]+=w0*h0.x; a0[1]+=w0*h0.y; a0[2]+=w0*h0.z; a0[3]+=w0*h0.w;
      a1[0]+=w1*h1.x; a1[1]+=w1*h1.y; a1[2]+=w1*h1.z; a1[3]+=w1*h1.w;
      a2[0]+=w2*h2.x; a2[1]+=w2*h2.y; a2[2]+=w2*h2.z; a2[3]+=w2*h2.w;
      a3[0]+=w3*h3.x; a3[1]+=w3*h3.y; a3[2]+=w3*h3.z; a3[3]+=w3*h3.w;
    }
    float r0v = ((a0[0]+a1[0])+(a2[0]+a3[0])) * inv;
    float r1v = ((a0[1]+a1[1])+(a2[1]+a3[1])) * inv;
    float r2v = ((a0[2]+a1[2])+(a2[2]+a3[2])) * inv;
    float r3v = ((a0[3]+a1[3])+(a2[3]+a3[3])) * inv;
    if (RELU){ r0v=fmaxf(r0v,0.f); r1v=fmaxf(r1v,0.f); r2v=fmaxf(r2v,0.f); r3v=fmaxf(r3v,0.f); }
    float4 o = make_float4(r0v, r1v, r2v, r3v);
    *(float4*)(out + (size_t)d * C + lane*4) = o;
  }
}

// ---------------------------------------------------------------- mu / logvar / z

__global__ void combine_w_kernel(const float* __restrict__ Wmu, const float* __restrict__ Wlv,
                                 float* __restrict__ Wc){
  int i = blockIdx.x*blockDim.x + threadIdx.x;
  if (i < 128*128){
    int k = i >> 7, c = i & 127;
    Wc[i] = (c < 64) ? Wmu[k*64 + c] : Wlv[k*64 + (c - 64)];
  }
}

__global__ void z_kernel(const float* __restrict__ mlv, const float* __restrict__ bmu,
                         const float* __restrict__ blv, const float* __restrict__ eps,
                         float* __restrict__ out_mu, float* __restrict__ out_lv,
                         float* __restrict__ out_z){
  int i = blockIdx.x*blockDim.x + threadIdx.x;
  if (i < N_NODES*64){
    int row = i >> 6, c = i & 63;
    float mu = mlv[(size_t)row*128 + c]      + bmu[c];
    float lv = mlv[(size_t)row*128 + 64 + c] + blv[c];
    float z  = eps[i] * __expf(0.5f * lv) + mu;
    out_mu[i] = mu; out_lv[i] = lv; out_z[i] = z;
  }
}

// ---------------------------------------------------------------- launch

extern "C" void kernel_launch(void* const* d_in, const int* in_sizes, int n_in,
                              void* d_out, int out_size, void* d_ws, size_t ws_size,
                              hipStream_t stream) {
  const float* x   = (const float*)d_in[0];
  const int*   ei  = (const int*)  d_in[1];
  const float* W1  = (const float*)d_in[2];
  const float* a1s = (const float*)d_in[3];
  const float* a1d = (const float*)d_in[4];
  const float* W2  = (const float*)d_in[5];
  const float* a2s = (const float*)d_in[6];
  const float* a2d = (const float*)d_in[7];
  const float* Wmu = (const float*)d_in[8];
  const float* bmu = (const float*)d_in[9];
  const float* Wlv = (const float*)d_in[10];
  const float* blv = (const float*)d_in[11];
  const float* W3  = (const float*)d_in[12];
  const float* a3s = (const float*)d_in[13];
  const float* a3d = (const float*)d_in[14];
  const float* W4  = (const float*)d_in[15];
  const float* a4s = (const float*)d_in[16];
  const float* a4d = (const float*)d_in[17];
  const float* eps = (const float*)d_in[18];

  float* out       = (float*)d_out;
  float* out_recon = out;                                   // [N,256]
  float* out_mu    = out + (size_t)N_NODES*256;             // [N,64]
  float* out_lv    = out_mu + (size_t)N_NODES*64;           // [N,64]
  float* out_z     = out_lv + (size_t)N_NODES*64;           // [N,64]

  char* wp = (char*)d_ws;
  auto alloc = [&](size_t bytes) -> void* {
    void* p = (void*)wp;
    wp += (bytes + 255) & ~(size_t)255;
    return p;
  };
  int*   deg    = (int*)  alloc((size_t)N_NODES*4);
  int*   nxt    = (int*)  alloc((size_t)N_NODES*4);
  int*   rowptr = (int*)  alloc((size_t)(N_NODES+1)*4);
  int*   incl   = (int*)  alloc((size_t)N_NODES*4);
  int*   bsum   = (int*)  alloc(64*4);
  int*   col    = (int*)  alloc((size_t)ETOT*4);
  float* bufPre = (float*)alloc((size_t)N_NODES*256*4);
  float* bufA   = (float*)alloc((size_t)N_NODES*128*4);
  float* bufB   = (float*)alloc((size_t)N_NODES*128*4);
  float* asb    = (float*)alloc((size_t)N_NODES*4);
  float* adb    = (float*)alloc((size_t)N_NODES*4);
  float* Wc     = (float*)alloc(128*128*4);

  // ---- CSR build
  zero_int_kernel<<<(N_NODES+255)/256, 256, 0, stream>>>(deg, N_NODES);
  hist_kernel<<<(ETOT+255)/256, 256, 0, stream>>>(ei, deg);
  const int nb = (N_NODES + 1023) / 1024;  // 49
  scan1_kernel<<<nb, 1024, 0, stream>>>(deg, incl, bsum, N_NODES);
  scan2_kernel<<<1, 64, 0, stream>>>(bsum, nb);
  scan3_kernel<<<(N_NODES+1+255)/256, 256, 0, stream>>>(incl, deg, bsum, rowptr, nxt, N_NODES);
  fill_kernel<<<(ETOT+255)/256, 256, 0, stream>>>(ei, nxt, col);

  const int NWG  = (N_NODES + 3) / 4;          // agg: 4 waves (nodes) per block
  const int G128 = (N_NODES + 127) / 128;      // gemm2 C=128 (TM=128)
  const int G64  = (N_NODES + 63) / 64;        // gemm2 C=256 (TM=64)

  // ---- layer 1: x(256) -> h1(128), relu
  gemm2_kernel<256,128,true><<<G128, 256, 0, stream>>>(x, W1, bufPre, a1s, a1d, asb, adb, N_NODES);
  agg_kernel<128,true><<<NWG, 256, 0, stream>>>(bufPre, asb, adb, rowptr, col, bufA, N_NODES);

  // ---- layer 2: h1(128) -> h2(128)
  gemm2_kernel<128,128,true><<<G128, 256, 0, stream>>>(bufA, W2, bufPre, a2s, a2d, asb, adb, N_NODES);
  agg_kernel<128,false><<<NWG, 256, 0, stream>>>(bufPre, asb, adb, rowptr, col, bufB, N_NODES);

  // ---- mu / logvar / z  (fused [Wmu|Wlv] GEMM, then elementwise)
  combine_w_kernel<<<(128*128+255)/256, 256, 0, stream>>>(Wmu, Wlv, Wc);
  gemm2_kernel<128,128,false><<<G128, 256, 0, stream>>>(bufB, Wc, bufPre, nullptr, nullptr, nullptr, nullptr, N_NODES);
  z_kernel<<<((int)((size_t)N_NODES*64+255)/256), 256, 0, stream>>>(bufPre, bmu, blv, eps,
                                                                    out_mu, out_lv, out_z);

  // ---- layer 3: z(64) -> h3(128), relu
  gemm2_kernel<64,128,true><<<G128, 256, 0, stream>>>(out_z, W3, bufPre, a3s, a3d, asb, adb, N_NODES);
  agg_kernel<128,true><<<NWG, 256, 0, stream>>>(bufPre, asb, adb, rowptr, col, bufA, N_NODES);

  // ---- layer 4: h3(128) -> recon(256)
  gemm2_kernel<128,256,true><<<G64, 256, 0, stream>>>(bufA, W4, bufPre, a4s, a4d, asb, adb, N_NODES);
  agg_kernel<256,false><<<NWG, 256, 0, stream>>>(bufPre, asb, adb, rowptr, col, out_recon, N_NODES);
}

// Round 6
// 931.355 us; speedup vs baseline: 1.3026x; 1.3026x over previous
//
#include <hip/hip_runtime.h>
#include <math.h>

#define N_NODES 50000
#define N_EDGES 800000
#define ETOT    850000   // N_EDGES + N_NODES self loops

static __device__ __forceinline__ float leaky(float v){ return v > 0.f ? v : 0.2f*v; }

// ---------------------------------------------------------------- CSR build

__global__ void zero_int_kernel(int* __restrict__ p, int n){
  int i = blockIdx.x*blockDim.x + threadIdx.x;
  if (i < n) p[i] = 0;
}

__global__ void hist_kernel(const int* __restrict__ ei, int* __restrict__ deg){
  int i = blockIdx.x*blockDim.x + threadIdx.x;
  if (i < ETOT){
    int d = (i < N_EDGES) ? ei[N_EDGES + i] : (i - N_EDGES);
    atomicAdd(&deg[d], 1);
  }
}

__global__ void scan1_kernel(const int* __restrict__ deg, int* __restrict__ incl,
                             int* __restrict__ bsum, int n){
  __shared__ int sm[1024];
  int i = blockIdx.x*1024 + threadIdx.x;
  int v = (i < n) ? deg[i] : 0;
  sm[threadIdx.x] = v;
  __syncthreads();
  for (int off = 1; off < 1024; off <<= 1){
    int t = (threadIdx.x >= off) ? sm[threadIdx.x - off] : 0;
    __syncthreads();
    sm[threadIdx.x] += t;
    __syncthreads();
  }
  if (i < n) incl[i] = sm[threadIdx.x];
  if (threadIdx.x == 1023) bsum[blockIdx.x] = sm[1023];
}

__global__ void scan2_kernel(int* __restrict__ bsum, int nb){
  if (threadIdx.x == 0 && blockIdx.x == 0){
    int acc = 0;
    for (int b = 0; b < nb; ++b){ int v = bsum[b]; bsum[b] = acc; acc += v; }
  }
}

__global__ void scan3_kernel(const int* __restrict__ incl, const int* __restrict__ deg,
                             const int* __restrict__ bsum, int* __restrict__ rowptr,
                             int* __restrict__ next, int n){
  int i = blockIdx.x*blockDim.x + threadIdx.x;
  if (i < n){
    int v = incl[i] - deg[i] + bsum[i >> 10];
    rowptr[i] = v;
    next[i]   = v;
  }
  if (i == n) rowptr[n] = ETOT;
}

__global__ void fill_kernel(const int* __restrict__ ei, int* __restrict__ next,
                            int* __restrict__ col){
  int i = blockIdx.x*blockDim.x + threadIdx.x;
  if (i < ETOT){
    int s, d;
    if (i < N_EDGES){ s = ei[i]; d = ei[N_EDGES + i]; }
    else            { s = i - N_EDGES; d = s; }
    int pos = atomicAdd(&next[d], 1);
    col[pos] = s;
  }
}

// ---------------------------------------------------------------- GEMM v2b (fp32, 8x8 thread tile)
// Y[M,C] = X[M,K] @ W[K,C], optional fused row-dots os = Y.a_s, od = Y.a_d.
// 256 threads = TXC col-threads x TYC row-threads; thread tile 8 rows x 8 cols.
// v2b fix: NO address-of-local-array anywhere (r5 profile showed acc/xr/wc
// spilled to scratch: VGPR=64, ~585MB phantom HBM traffic per dispatch).
// LDS reads land in float4 VALUES; stores rebuilt via make_float4.

template<int K, int C, bool DOT>
__launch_bounds__(256, 2)
__global__ void gemm2_kernel(const float* __restrict__ X, const float* __restrict__ W,
                             float* __restrict__ Y,
                             const float* __restrict__ a_s, const float* __restrict__ a_d,
                             float* __restrict__ os, float* __restrict__ od, int M)
{
  constexpr int TXC = C / 8;          // 16 (C=128) or 32 (C=256)
  constexpr int TYC = 256 / TXC;      // 16 or 8
  constexpr int TM  = TYC * 8;        // 128 or 64
  constexpr int KT  = 32;
  constexpr int HC  = C / 2;
  constexpr int F4  = KT / 4;         // 8

  __shared__ float Xt[KT][TM + 4];    // k-major; +4 keeps rows 16B-aligned, shifts banks
  __shared__ float Ws[KT][C];

  const int t  = threadIdx.x;
  const int tx = t % TXC;
  const int ty = t / TXC;
  const int r0 = blockIdx.x * TM;

  float acc[8][8];                    // constant-indexed only (full unroll) -> stays in VGPRs
  #pragma unroll
  for (int r = 0; r < 8; ++r)
    #pragma unroll
    for (int c = 0; c < 8; ++c) acc[r][c] = 0.f;

  for (int kt = 0; kt < K; kt += KT){
    // stage W tile (linear copy, KT rows of C floats)
    {
      const float4* wsrc = (const float4*)(W + (size_t)kt * C);
      float4* wdst = (float4*)(&Ws[0][0]);
      #pragma unroll
      for (int i = t; i < KT * C / 4; i += 256) wdst[i] = wsrc[i];
    }
    // stage X tile transposed: read float4 along k, scatter to k-major rows
    #pragma unroll
    for (int i = t; i < TM * F4; i += 256){
      int row = i / F4;
      int fq  = i % F4;
      float4 v = make_float4(0.f, 0.f, 0.f, 0.f);
      int gr = r0 + row;
      if (gr < M) v = *(const float4*)(X + (size_t)gr * K + kt + fq * 4);
      Xt[fq*4+0][row] = v.x; Xt[fq*4+1][row] = v.y;
      Xt[fq*4+2][row] = v.z; Xt[fq*4+3][row] = v.w;
    }
    __syncthreads();

    #pragma unroll
    for (int k = 0; k < KT; ++k){
      const float4 xa = *(const float4*)&Xt[k][ty*8];
      const float4 xb = *(const float4*)&Xt[k][ty*8 + 4];
      const float4 wa = *(const float4*)&Ws[k][tx*4];
      const float4 wb = *(const float4*)&Ws[k][HC + tx*4];
      const float xr[8] = {xa.x, xa.y, xa.z, xa.w, xb.x, xb.y, xb.z, xb.w};
      const float wc[8] = {wa.x, wa.y, wa.z, wa.w, wb.x, wb.y, wb.z, wb.w};
      #pragma unroll
      for (int r = 0; r < 8; ++r)
        #pragma unroll
        for (int c = 0; c < 8; ++c)
          acc[r][c] += xr[r] * wc[c];
    }
    __syncthreads();
  }

  #pragma unroll
  for (int r = 0; r < 8; ++r){
    int row = r0 + ty*8 + r;
    if (row < M){
      *(float4*)(Y + (size_t)row * C + tx*4)
          = make_float4(acc[r][0], acc[r][1], acc[r][2], acc[r][3]);
      *(float4*)(Y + (size_t)row * C + HC + tx*4)
          = make_float4(acc[r][4], acc[r][5], acc[r][6], acc[r][7]);
    }
  }

  if constexpr (DOT){
    const float4 as0 = *(const float4*)(a_s + tx*4);
    const float4 as1 = *(const float4*)(a_s + HC + tx*4);
    const float4 ad0 = *(const float4*)(a_d + tx*4);
    const float4 ad1 = *(const float4*)(a_d + HC + tx*4);
    #pragma unroll
    for (int r = 0; r < 8; ++r){
      float ps = acc[r][0]*as0.x + acc[r][1]*as0.y + acc[r][2]*as0.z + acc[r][3]*as0.w
               + acc[r][4]*as1.x + acc[r][5]*as1.y + acc[r][6]*as1.z + acc[r][7]*as1.w;
      float pd = acc[r][0]*ad0.x + acc[r][1]*ad0.y + acc[r][2]*ad0.z + acc[r][3]*ad0.w
               + acc[r][4]*ad1.x + acc[r][5]*ad1.y + acc[r][6]*ad1.z + acc[r][7]*ad1.w;
      #pragma unroll
      for (int off = TXC/2; off; off >>= 1){
        ps += __shfl_xor(ps, off);
        pd += __shfl_xor(pd, off);
      }
      int row = r0 + ty*8 + r;
      if (tx == 0 && row < M){ os[row] = ps; od[row] = pd; }
    }
  }
}

// ---------------------------------------------------------------- edge-softmax aggregation
// one wave per destination node; CSR over incoming edges; message loop unrolled x4.

template<int C, bool RELU>
__global__ void agg_kernel(const float* __restrict__ h, const float* __restrict__ as_,
                           const float* __restrict__ ad_, const int* __restrict__ rowptr,
                           const int* __restrict__ col, float* __restrict__ out, int n){
  int d    = (blockIdx.x * blockDim.x + threadIdx.x) >> 6;
  int lane = threadIdx.x & 63;
  if (d >= n) return;
  int beg = rowptr[d], end = rowptr[d+1];
  float add = ad_[d];

  float m = -INFINITY;
  for (int e = beg + lane; e < end; e += 64)
    m = fmaxf(m, leaky(as_[col[e]] + add));
  #pragma unroll
  for (int off = 32; off; off >>= 1) m = fmaxf(m, __shfl_xor(m, off));

  float ssum = 0.f;
  for (int e = beg + lane; e < end; e += 64)
    ssum += __expf(leaky(as_[col[e]] + add) - m);
  #pragma unroll
  for (int off = 32; off; off >>= 1) ssum += __shfl_xor(ssum, off);
  float inv = 1.f / (ssum + 1e-16f);

  const int last = end - 1;

  if constexpr (C == 128){
    float ax0=0.f,ay0=0.f, ax1=0.f,ay1=0.f, ax2=0.f,ay2=0.f, ax3=0.f,ay3=0.f;
    for (int e = beg; e < end; e += 4){
      int e1 = e+1 <= last ? e+1 : last;
      int e2 = e+2 <= last ? e+2 : last;
      int e3 = e+3 <= last ? e+3 : last;
      int s0 = col[e], s1 = col[e1], s2 = col[e2], s3 = col[e3];
      float w0 = __expf(leaky(as_[s0] + add) - m);
      float w1 = (e+1 <= last) ? __expf(leaky(as_[s1] + add) - m) : 0.f;
      float w2 = (e+2 <= last) ? __expf(leaky(as_[s2] + add) - m) : 0.f;
      float w3 = (e+3 <= last) ? __expf(leaky(as_[s3] + add) - m) : 0.f;
      float2 h0 = *(const float2*)(h + (size_t)s0 * C + lane*2);
      float2 h1 = *(const float2*)(h + (size_t)s1 * C + lane*2);
      float2 h2 = *(const float2*)(h + (size_t)s2 * C + lane*2);
      float2 h3 = *(const float2*)(h + (size_t)s3 * C + lane*2);
      ax0 += w0*h0.x; ay0 += w0*h0.y;
      ax1 += w1*h1.x; ay1 += w1*h1.y;
      ax2 += w2*h2.x; ay2 += w2*h2.y;
      ax3 += w3*h3.x; ay3 += w3*h3.y;
    }
    float ax = ((ax0+ax1)+(ax2+ax3)) * inv;
    float ay = ((ay0+ay1)+(ay2+ay3)) * inv;
    if (RELU){ ax = fmaxf(ax, 0.f); ay = fmaxf(ay, 0.f); }
    float2 o; o.x = ax; o.y = ay;
    *(float2*)(out + (size_t)d * C + lane*2) = o;
  } else {
    float a0[4]={0,0,0,0}, a1[4]={0,0,0,0}, a2[4]={0,0,0,0}, a3[4]={0,0,0,0};
    for (int e = beg; e < end; e += 4){
      int e1 = e+1 <= last ? e+1 : last;
      int e2 = e+2 <= last ? e+2 : last;
      int e3 = e+3 <= last ? e+3 : last;
      int s0 = col[e], s1 = col[e1], s2 = col[e2], s3 = col[e3];
      float w0 = __expf(leaky(as_[s0] + add) - m);
      float w1 = (e+1 <= last) ? __expf(leaky(as_[s1] + add) - m) : 0.f;
      float w2 = (e+2 <= last) ? __expf(leaky(as_[s2] + add) - m) : 0.f;
      float w3 = (e+3 <= last) ? __expf(leaky(as_[s3] + add) - m) : 0.f;
      float4 h0 = *(const float4*)(h + (size_t)s0 * C + lane*4);
      float4 h1 = *(const float4*)(h + (size_t)s1 * C + lane*4);
      float4 h2 = *(const float4*)(h + (size_t)s2 * C + lane*4);
      float4 h3 = *(const float4*)(h + (size_t)s3 * C + lane*4);
      a0[0]+=w0*h0.x; a0[1]+=w0*h0.y; a0[2]+=w0*h0.z; a0[3]+=w0*h0.w;
      a1[0]+=w1*h1.x; a1[1]+=w1*h1.y; a1[2]+=w1*h1.z; a1[3]+=w1*h1.w;
      a2[0]+=w2*h2.x; a2[1]+=w2*h2.y; a2[2]+=w2*h2.z; a2[3]+=w2*h2.w;
      a3[0]+=w3*h3.x; a3[1]+=w3*h3.y; a3[2]+=w3*h3.z; a3[3]+=w3*h3.w;
    }
    float r0v = ((a0[0]+a1[0])+(a2[0]+a3[0])) * inv;
    float r1v = ((a0[1]+a1[1])+(a2[1]+a3[1])) * inv;
    float r2v = ((a0[2]+a1[2])+(a2[2]+a3[2])) * inv;
    float r3v = ((a0[3]+a1[3])+(a2[3]+a3[3])) * inv;
    if (RELU){ r0v=fmaxf(r0v,0.f); r1v=fmaxf(r1v,0.f); r2v=fmaxf(r2v,0.f); r3v=fmaxf(r3v,0.f); }
    float4 o = make_float4(r0v, r1v, r2v, r3v);
    *(float4*)(out + (size_t)d * C + lane*4) = o;
  }
}

// ---------------------------------------------------------------- mu / logvar / z

__global__ void combine_w_kernel(const float* __restrict__ Wmu, const float* __restrict__ Wlv,
                                 float* __restrict__ Wc){
  int i = blockIdx.x*blockDim.x + threadIdx.x;
  if (i < 128*128){
    int k = i >> 7, c = i & 127;
    Wc[i] = (c < 64) ? Wmu[k*64 + c] : Wlv[k*64 + (c - 64)];
  }
}

__global__ void z_kernel(const float* __restrict__ mlv, const float* __restrict__ bmu,
                         const float* __restrict__ blv, const float* __restrict__ eps,
                         float* __restrict__ out_mu, float* __restrict__ out_lv,
                         float* __restrict__ out_z){
  int i = blockIdx.x*blockDim.x + threadIdx.x;
  if (i < N_NODES*64){
    int row = i >> 6, c = i & 63;
    float mu = mlv[(size_t)row*128 + c]      + bmu[c];
    float lv = mlv[(size_t)row*128 + 64 + c] + blv[c];
    float z  = eps[i] * __expf(0.5f * lv) + mu;
    out_mu[i] = mu; out_lv[i] = lv; out_z[i] = z;
  }
}

// ---------------------------------------------------------------- launch

extern "C" void kernel_launch(void* const* d_in, const int* in_sizes, int n_in,
                              void* d_out, int out_size, void* d_ws, size_t ws_size,
                              hipStream_t stream) {
  const float* x   = (const float*)d_in[0];
  const int*   ei  = (const int*)  d_in[1];
  const float* W1  = (const float*)d_in[2];
  const float* a1s = (const float*)d_in[3];
  const float* a1d = (const float*)d_in[4];
  const float* W2  = (const float*)d_in[5];
  const float* a2s = (const float*)d_in[6];
  const float* a2d = (const float*)d_in[7];
  const float* Wmu = (const float*)d_in[8];
  const float* bmu = (const float*)d_in[9];
  const float* Wlv = (const float*)d_in[10];
  const float* blv = (const float*)d_in[11];
  const float* W3  = (const float*)d_in[12];
  const float* a3s = (const float*)d_in[13];
  const float* a3d = (const float*)d_in[14];
  const float* W4  = (const float*)d_in[15];
  const float* a4s = (const float*)d_in[16];
  const float* a4d = (const float*)d_in[17];
  const float* eps = (const float*)d_in[18];

  float* out       = (float*)d_out;
  float* out_recon = out;                                   // [N,256]
  float* out_mu    = out + (size_t)N_NODES*256;             // [N,64]
  float* out_lv    = out_mu + (size_t)N_NODES*64;           // [N,64]
  float* out_z     = out_lv + (size_t)N_NODES*64;           // [N,64]

  char* wp = (char*)d_ws;
  auto alloc = [&](size_t bytes) -> void* {
    void* p = (void*)wp;
    wp += (bytes + 255) & ~(size_t)255;
    return p;
  };
  int*   deg    = (int*)  alloc((size_t)N_NODES*4);
  int*   nxt    = (int*)  alloc((size_t)N_NODES*4);
  int*   rowptr = (int*)  alloc((size_t)(N_NODES+1)*4);
  int*   incl   = (int*)  alloc((size_t)N_NODES*4);
  int*   bsum   = (int*)  alloc(64*4);
  int*   col    = (int*)  alloc((size_t)ETOT*4);
  float* bufPre = (float*)alloc((size_t)N_NODES*256*4);
  float* bufA   = (float*)alloc((size_t)N_NODES*128*4);
  float* bufB   = (float*)alloc((size_t)N_NODES*128*4);
  float* asb    = (float*)alloc((size_t)N_NODES*4);
  float* adb    = (float*)alloc((size_t)N_NODES*4);
  float* Wc     = (float*)alloc(128*128*4);

  // ---- CSR build
  zero_int_kernel<<<(N_NODES+255)/256, 256, 0, stream>>>(deg, N_NODES);
  hist_kernel<<<(ETOT+255)/256, 256, 0, stream>>>(ei, deg);
  const int nb = (N_NODES + 1023) / 1024;  // 49
  scan1_kernel<<<nb, 1024, 0, stream>>>(deg, incl, bsum, N_NODES);
  scan2_kernel<<<1, 64, 0, stream>>>(bsum, nb);
  scan3_kernel<<<(N_NODES+1+255)/256, 256, 0, stream>>>(incl, deg, bsum, rowptr, nxt, N_NODES);
  fill_kernel<<<(ETOT+255)/256, 256, 0, stream>>>(ei, nxt, col);

  const int NWG  = (N_NODES + 3) / 4;          // agg: 4 waves (nodes) per block
  const int G128 = (N_NODES + 127) / 128;      // gemm2 C=128 (TM=128)
  const int G64  = (N_NODES + 63) / 64;        // gemm2 C=256 (TM=64)

  // ---- layer 1: x(256) -> h1(128), relu
  gemm2_kernel<256,128,true><<<G128, 256, 0, stream>>>(x, W1, bufPre, a1s, a1d, asb, adb, N_NODES);
  agg_kernel<128,true><<<NWG, 256, 0, stream>>>(bufPre, asb, adb, rowptr, col, bufA, N_NODES);

  // ---- layer 2: h1(128) -> h2(128)
  gemm2_kernel<128,128,true><<<G128, 256, 0, stream>>>(bufA, W2, bufPre, a2s, a2d, asb, adb, N_NODES);
  agg_kernel<128,false><<<NWG, 256, 0, stream>>>(bufPre, asb, adb, rowptr, col, bufB, N_NODES);

  // ---- mu / logvar / z  (fused [Wmu|Wlv] GEMM, then elementwise)
  combine_w_kernel<<<(128*128+255)/256, 256, 0, stream>>>(Wmu, Wlv, Wc);
  gemm2_kernel<128,128,false><<<G128, 256, 0, stream>>>(bufB, Wc, bufPre, nullptr, nullptr, nullptr, nullptr, N_NODES);
  z_kernel<<<((int)((size_t)N_NODES*64+255)/256), 256, 0, stream>>>(bufPre, bmu, blv, eps,
                                                                    out_mu, out_lv, out_z);

  // ---- layer 3: z(64) -> h3(128), relu
  gemm2_kernel<64,128,true><<<G128, 256, 0, stream>>>(out_z, W3, bufPre, a3s, a3d, asb, adb, N_NODES);
  agg_kernel<128,true><<<NWG, 256, 0, stream>>>(bufPre, asb, adb, rowptr, col, bufA, N_NODES);

  // ---- layer 4: h3(128) -> recon(256)
  gemm2_kernel<128,256,true><<<G64, 256, 0, stream>>>(bufA, W4, bufPre, a4s, a4d, asb, adb, N_NODES);
  agg_kernel<256,false><<<NWG, 256, 0, stream>>>(bufPre, asb, adb, rowptr, col, out_recon, N_NODES);
}

// Round 7
// 707.041 us; speedup vs baseline: 1.7159x; 1.3173x over previous
//
#include <hip/hip_runtime.h>
#include <math.h>

#define N_NODES 50000
#define N_EDGES 800000
#define ETOT    850000   // N_EDGES + N_NODES self loops

static __device__ __forceinline__ float leaky(float v){ return v > 0.f ? v : 0.2f*v; }

// ---------------------------------------------------------------- CSR build

__global__ void zero_int_kernel(int* __restrict__ p, int n){
  int i = blockIdx.x*blockDim.x + threadIdx.x;
  if (i < n) p[i] = 0;
}

__global__ void hist_kernel(const int* __restrict__ ei, int* __restrict__ deg){
  int i = blockIdx.x*blockDim.x + threadIdx.x;
  if (i < ETOT){
    int d = (i < N_EDGES) ? ei[N_EDGES + i] : (i - N_EDGES);
    atomicAdd(&deg[d], 1);
  }
}

__global__ void scan1_kernel(const int* __restrict__ deg, int* __restrict__ incl,
                             int* __restrict__ bsum, int n){
  __shared__ int sm[1024];
  int i = blockIdx.x*1024 + threadIdx.x;
  int v = (i < n) ? deg[i] : 0;
  sm[threadIdx.x] = v;
  __syncthreads();
  for (int off = 1; off < 1024; off <<= 1){
    int t = (threadIdx.x >= off) ? sm[threadIdx.x - off] : 0;
    __syncthreads();
    sm[threadIdx.x] += t;
    __syncthreads();
  }
  if (i < n) incl[i] = sm[threadIdx.x];
  if (threadIdx.x == 1023) bsum[blockIdx.x] = sm[1023];
}

__global__ void scan2_kernel(int* __restrict__ bsum, int nb){
  if (threadIdx.x == 0 && blockIdx.x == 0){
    int acc = 0;
    for (int b = 0; b < nb; ++b){ int v = bsum[b]; bsum[b] = acc; acc += v; }
  }
}

__global__ void scan3_kernel(const int* __restrict__ incl, const int* __restrict__ deg,
                             const int* __restrict__ bsum, int* __restrict__ rowptr,
                             int* __restrict__ next, int n){
  int i = blockIdx.x*blockDim.x + threadIdx.x;
  if (i < n){
    int v = incl[i] - deg[i] + bsum[i >> 10];
    rowptr[i] = v;
    next[i]   = v;
  }
  if (i == n) rowptr[n] = ETOT;
}

__global__ void fill_kernel(const int* __restrict__ ei, int* __restrict__ next,
                            int* __restrict__ col){
  int i = blockIdx.x*blockDim.x + threadIdx.x;
  if (i < ETOT){
    int s, d;
    if (i < N_EDGES){ s = ei[i]; d = ei[N_EDGES + i]; }
    else            { s = i - N_EDGES; d = s; }
    int pos = atomicAdd(&next[d], 1);
    col[pos] = s;
  }
}

// ---------------------------------------------------------------- small matvec: cs[k]=W[k,:].as, cd[k]=W[k,:].ad
// one wave per output row.

template<int KR, int CC>
__global__ void matvec2_kernel(const float* __restrict__ W, const float* __restrict__ a_s,
                               const float* __restrict__ a_d, float* __restrict__ cs,
                               float* __restrict__ cd){
  int w    = (blockIdx.x*blockDim.x + threadIdx.x) >> 6;
  int lane = threadIdx.x & 63;
  if (w >= KR) return;
  const float* row = W + (size_t)w * CC;
  float ps = 0.f, pd = 0.f;
  #pragma unroll
  for (int i = 0; i < CC/64; ++i){
    float x = row[lane + i*64];
    ps += x * a_s[lane + i*64];
    pd += x * a_d[lane + i*64];
  }
  #pragma unroll
  for (int off = 32; off; off >>= 1){
    ps += __shfl_xor(ps, off);
    pd += __shfl_xor(pd, off);
  }
  if (lane == 0){ cs[w] = ps; cd[w] = pd; }
}

// ---------------------------------------------------------------- GEMM (fp32, 8x8 thread tile)
// Y[M,C] = X[M,K] @ W[K,C]; optional fused RELU; optional fused row-dots on the
// (relu'd) output: os = Y.a_s, od = Y.a_d.
// NOTE: no address-of-local anywhere (r5: pointer-cast locals spilled to scratch).

template<int K, int C, bool DOT, bool RELU>
__launch_bounds__(256, 2)
__global__ void gemm2_kernel(const float* __restrict__ X, const float* __restrict__ W,
                             float* __restrict__ Y,
                             const float* __restrict__ a_s, const float* __restrict__ a_d,
                             float* __restrict__ os, float* __restrict__ od, int M)
{
  constexpr int TXC = C / 8;          // 16 (C=128) or 32 (C=256)
  constexpr int TYC = 256 / TXC;      // 16 or 8
  constexpr int TM  = TYC * 8;        // 128 or 64
  constexpr int KT  = 32;
  constexpr int HC  = C / 2;
  constexpr int F4  = KT / 4;         // 8

  __shared__ float Xt[KT][TM + 4];
  __shared__ float Ws[KT][C];

  const int t  = threadIdx.x;
  const int tx = t % TXC;
  const int ty = t / TXC;
  const int r0 = blockIdx.x * TM;

  float acc[8][8];
  #pragma unroll
  for (int r = 0; r < 8; ++r)
    #pragma unroll
    for (int c = 0; c < 8; ++c) acc[r][c] = 0.f;

  for (int kt = 0; kt < K; kt += KT){
    {
      const float4* wsrc = (const float4*)(W + (size_t)kt * C);
      float4* wdst = (float4*)(&Ws[0][0]);
      #pragma unroll
      for (int i = t; i < KT * C / 4; i += 256) wdst[i] = wsrc[i];
    }
    #pragma unroll
    for (int i = t; i < TM * F4; i += 256){
      int row = i / F4;
      int fq  = i % F4;
      float4 v = make_float4(0.f, 0.f, 0.f, 0.f);
      int gr = r0 + row;
      if (gr < M) v = *(const float4*)(X + (size_t)gr * K + kt + fq * 4);
      Xt[fq*4+0][row] = v.x; Xt[fq*4+1][row] = v.y;
      Xt[fq*4+2][row] = v.z; Xt[fq*4+3][row] = v.w;
    }
    __syncthreads();

    #pragma unroll
    for (int k = 0; k < KT; ++k){
      const float4 xa = *(const float4*)&Xt[k][ty*8];
      const float4 xb = *(const float4*)&Xt[k][ty*8 + 4];
      const float4 wa = *(const float4*)&Ws[k][tx*4];
      const float4 wb = *(const float4*)&Ws[k][HC + tx*4];
      const float xr[8] = {xa.x, xa.y, xa.z, xa.w, xb.x, xb.y, xb.z, xb.w};
      const float wc[8] = {wa.x, wa.y, wa.z, wa.w, wb.x, wb.y, wb.z, wb.w};
      #pragma unroll
      for (int r = 0; r < 8; ++r)
        #pragma unroll
        for (int c = 0; c < 8; ++c)
          acc[r][c] += xr[r] * wc[c];
    }
    __syncthreads();
  }

  if constexpr (RELU){
    #pragma unroll
    for (int r = 0; r < 8; ++r)
      #pragma unroll
      for (int c = 0; c < 8; ++c) acc[r][c] = fmaxf(acc[r][c], 0.f);
  }

  #pragma unroll
  for (int r = 0; r < 8; ++r){
    int row = r0 + ty*8 + r;
    if (row < M){
      *(float4*)(Y + (size_t)row * C + tx*4)
          = make_float4(acc[r][0], acc[r][1], acc[r][2], acc[r][3]);
      *(float4*)(Y + (size_t)row * C + HC + tx*4)
          = make_float4(acc[r][4], acc[r][5], acc[r][6], acc[r][7]);
    }
  }

  if constexpr (DOT){
    const float4 as0 = *(const float4*)(a_s + tx*4);
    const float4 as1 = *(const float4*)(a_s + HC + tx*4);
    const float4 ad0 = *(const float4*)(a_d + tx*4);
    const float4 ad1 = *(const float4*)(a_d + HC + tx*4);
    #pragma unroll
    for (int r = 0; r < 8; ++r){
      float ps = acc[r][0]*as0.x + acc[r][1]*as0.y + acc[r][2]*as0.z + acc[r][3]*as0.w
               + acc[r][4]*as1.x + acc[r][5]*as1.y + acc[r][6]*as1.z + acc[r][7]*as1.w;
      float pd = acc[r][0]*ad0.x + acc[r][1]*ad0.y + acc[r][2]*ad0.z + acc[r][3]*ad0.w
               + acc[r][4]*ad1.x + acc[r][5]*ad1.y + acc[r][6]*ad1.z + acc[r][7]*ad1.w;
      #pragma unroll
      for (int off = TXC/2; off; off >>= 1){
        ps += __shfl_xor(ps, off);
        pd += __shfl_xor(pd, off);
      }
      int row = r0 + ty*8 + r;
      if (tx == 0 && row < M){ os[row] = ps; od[row] = pd; }
    }
  }
}

// ---------------------------------------------------------------- edge-softmax aggregation v3
// one wave per destination node. Single score-gather pass; exp computed once
// per edge (lane-parallel); weights parked in LDS; lean gather+FMA message loop.
// Fallback (recompute) path for deg>128.

template<int C, bool RELU>
__global__ void agg3_kernel(const float* __restrict__ h, const float* __restrict__ as_,
                            const float* __restrict__ ad_, const int* __restrict__ rowptr,
                            const int* __restrict__ col, float* __restrict__ out, int n){
  __shared__ float wls[4][136];
  const int wv   = threadIdx.x >> 6;
  const int lane = threadIdx.x & 63;
  const int d    = blockIdx.x*4 + wv;
  if (d >= n) return;
  const int beg = rowptr[d], end = rowptr[d+1];
  const int deg = end - beg, last = end - 1;
  const float add = ad_[d];

  const bool fast = (deg <= 128);
  float inv, mG = 0.f;
  if (fast){
    const int e0 = beg + lane, e1 = beg + 64 + lane;
    float s0 = (e0 < end) ? leaky(as_[col[e0]] + add) : -INFINITY;
    float s1 = (e1 < end) ? leaky(as_[col[e1]] + add) : -INFINITY;
    float m = fmaxf(s0, s1);
    #pragma unroll
    for (int off = 32; off; off >>= 1) m = fmaxf(m, __shfl_xor(m, off));
    float w0 = __expf(s0 - m), w1 = __expf(s1 - m);   // exp(-inf)=0 for pad lanes
    wls[wv][lane] = w0; wls[wv][64 + lane] = w1;
    if (lane < 8) wls[wv][128 + lane] = 0.f;
    float ss = w0 + w1;
    #pragma unroll
    for (int off = 32; off; off >>= 1) ss += __shfl_xor(ss, off);
    inv = 1.f / (ss + 1e-16f);
  } else {
    float m = -INFINITY;
    for (int e = beg + lane; e < end; e += 64) m = fmaxf(m, leaky(as_[col[e]] + add));
    #pragma unroll
    for (int off = 32; off; off >>= 1) m = fmaxf(m, __shfl_xor(m, off));
    float ss = 0.f;
    for (int e = beg + lane; e < end; e += 64) ss += __expf(leaky(as_[col[e]] + add) - m);
    #pragma unroll
    for (int off = 32; off; off >>= 1) ss += __shfl_xor(ss, off);
    inv = 1.f / (ss + 1e-16f);
    mG = m;
  }

  if constexpr (C == 128){
    float ax0=0.f,ay0=0.f, ax1=0.f,ay1=0.f, ax2=0.f,ay2=0.f, ax3=0.f,ay3=0.f;
    if (fast){
      for (int e = beg; e < end; e += 4){
        const float4 w4 = *(const float4*)&wls[wv][e - beg];  // pad-safe: [deg..131]=0
        int c0 = col[e];
        int c1 = col[e+1 <= last ? e+1 : last];
        int c2 = col[e+2 <= last ? e+2 : last];
        int c3 = col[e+3 <= last ? e+3 : last];
        float2 h0 = *(const float2*)(h + (size_t)c0 * C + lane*2);
        float2 h1 = *(const float2*)(h + (size_t)c1 * C + lane*2);
        float2 h2 = *(const float2*)(h + (size_t)c2 * C + lane*2);
        float2 h3 = *(const float2*)(h + (size_t)c3 * C + lane*2);
        ax0 += w4.x*h0.x; ay0 += w4.x*h0.y;
        ax1 += w4.y*h1.x; ay1 += w4.y*h1.y;
        ax2 += w4.z*h2.x; ay2 += w4.z*h2.y;
        ax3 += w4.w*h3.x; ay3 += w4.w*h3.y;
      }
    } else {
      for (int e = beg; e < end; ++e){
        int s = col[e];
        float w = __expf(leaky(as_[s] + add) - mG);
        float2 hv = *(const float2*)(h + (size_t)s * C + lane*2);
        ax0 += w*hv.x; ay0 += w*hv.y;
      }
    }
    float ax = ((ax0+ax1)+(ax2+ax3)) * inv;
    float ay = ((ay0+ay1)+(ay2+ay3)) * inv;
    if (RELU){ ax = fmaxf(ax, 0.f); ay = fmaxf(ay, 0.f); }
    float2 o; o.x = ax; o.y = ay;
    *(float2*)(out + (size_t)d * C + lane*2) = o;
  } else {            // C == 64: one float per lane
    float a0=0.f, a1=0.f, a2=0.f, a3=0.f;
    if (fast){
      for (int e = beg; e < end; e += 4){
        const float4 w4 = *(const float4*)&wls[wv][e - beg];
        int c0 = col[e];
        int c1 = col[e+1 <= last ? e+1 : last];
        int c2 = col[e+2 <= last ? e+2 : last];
        int c3 = col[e+3 <= last ? e+3 : last];
        a0 += w4.x * h[(size_t)c0 * C + lane];
        a1 += w4.y * h[(size_t)c1 * C + lane];
        a2 += w4.z * h[(size_t)c2 * C + lane];
        a3 += w4.w * h[(size_t)c3 * C + lane];
      }
    } else {
      for (int e = beg; e < end; ++e){
        int s = col[e];
        float w = __expf(leaky(as_[s] + add) - mG);
        a0 += w * h[(size_t)s * C + lane];
      }
    }
    float av = ((a0+a1)+(a2+a3)) * inv;
    if (RELU) av = fmaxf(av, 0.f);
    out[(size_t)d * C + lane] = av;
  }
}

// ---------------------------------------------------------------- mu / logvar / z (+ fused L3 score rowdot on z)

__global__ void combine_w_kernel(const float* __restrict__ Wmu, const float* __restrict__ Wlv,
                                 float* __restrict__ Wc){
  int i = blockIdx.x*blockDim.x + threadIdx.x;
  if (i < 128*128){
    int k = i >> 7, c = i & 127;
    Wc[i] = (c < 64) ? Wmu[k*64 + c] : Wlv[k*64 + (c - 64)];
  }
}

__global__ void z_kernel(const float* __restrict__ mlv, const float* __restrict__ bmu,
                         const float* __restrict__ blv, const float* __restrict__ eps,
                         const float* __restrict__ c3s, const float* __restrict__ c3d,
                         float* __restrict__ out_mu, float* __restrict__ out_lv,
                         float* __restrict__ out_z,
                         float* __restrict__ os, float* __restrict__ od){
  // grid is exact: N_NODES*64 threads; each wave covers exactly one row.
  int i = blockIdx.x*blockDim.x + threadIdx.x;
  int row = i >> 6, c = i & 63;
  float mu = mlv[(size_t)row*128 + c]      + bmu[c];
  float lv = mlv[(size_t)row*128 + 64 + c] + blv[c];
  float z  = eps[i] * __expf(0.5f * lv) + mu;
  out_mu[i] = mu; out_lv[i] = lv; out_z[i] = z;
  float ps = z * c3s[c], pd = z * c3d[c];
  #pragma unroll
  for (int off = 32; off; off >>= 1){
    ps += __shfl_xor(ps, off);
    pd += __shfl_xor(pd, off);
  }
  if (c == 0){ os[row] = ps; od[row] = pd; }
}

// ---------------------------------------------------------------- launch

extern "C" void kernel_launch(void* const* d_in, const int* in_sizes, int n_in,
                              void* d_out, int out_size, void* d_ws, size_t ws_size,
                              hipStream_t stream) {
  const float* x   = (const float*)d_in[0];
  const int*   ei  = (const int*)  d_in[1];
  const float* W1  = (const float*)d_in[2];
  const float* a1s = (const float*)d_in[3];
  const float* a1d = (const float*)d_in[4];
  const float* W2  = (const float*)d_in[5];
  const float* a2s = (const float*)d_in[6];
  const float* a2d = (const float*)d_in[7];
  const float* Wmu = (const float*)d_in[8];
  const float* bmu = (const float*)d_in[9];
  const float* Wlv = (const float*)d_in[10];
  const float* blv = (const float*)d_in[11];
  const float* W3  = (const float*)d_in[12];
  const float* a3s = (const float*)d_in[13];
  const float* a3d = (const float*)d_in[14];
  const float* W4  = (const float*)d_in[15];
  const float* a4s = (const float*)d_in[16];
  const float* a4d = (const float*)d_in[17];
  const float* eps = (const float*)d_in[18];

  float* out       = (float*)d_out;
  float* out_recon = out;                                   // [N,256]
  float* out_mu    = out + (size_t)N_NODES*256;             // [N,64]
  float* out_lv    = out_mu + (size_t)N_NODES*64;           // [N,64]
  float* out_z     = out_lv + (size_t)N_NODES*64;           // [N,64]

  char* wp = (char*)d_ws;
  auto alloc = [&](size_t bytes) -> void* {
    void* p = (void*)wp;
    wp += (bytes + 255) & ~(size_t)255;
    return p;
  };
  int*   deg    = (int*)  alloc((size_t)N_NODES*4);
  int*   nxt    = (int*)  alloc((size_t)N_NODES*4);
  int*   rowptr = (int*)  alloc((size_t)(N_NODES+1)*4);
  int*   incl   = (int*)  alloc((size_t)N_NODES*4);
  int*   bsum   = (int*)  alloc(64*4);
  int*   col    = (int*)  alloc((size_t)ETOT*4);
  float* bufPre = (float*)alloc((size_t)N_NODES*256*4);
  float* bufA   = (float*)alloc((size_t)N_NODES*128*4);
  float* bufB   = (float*)alloc((size_t)N_NODES*128*4);
  float* asb    = (float*)alloc((size_t)N_NODES*4);
  float* adb    = (float*)alloc((size_t)N_NODES*4);
  float* Wc     = (float*)alloc(128*128*4);
  float* c3s    = (float*)alloc(64*4);
  float* c3d    = (float*)alloc(64*4);
  float* c4s    = (float*)alloc(128*4);
  float* c4d    = (float*)alloc(128*4);

  // ---- CSR build
  zero_int_kernel<<<(N_NODES+255)/256, 256, 0, stream>>>(deg, N_NODES);
  hist_kernel<<<(ETOT+255)/256, 256, 0, stream>>>(ei, deg);
  const int nb = (N_NODES + 1023) / 1024;  // 49
  scan1_kernel<<<nb, 1024, 0, stream>>>(deg, incl, bsum, N_NODES);
  scan2_kernel<<<1, 64, 0, stream>>>(bsum, nb);
  scan3_kernel<<<(N_NODES+1+255)/256, 256, 0, stream>>>(incl, deg, bsum, rowptr, nxt, N_NODES);
  fill_kernel<<<(ETOT+255)/256, 256, 0, stream>>>(ei, nxt, col);

  // ---- commuted-score vectors: c3 = W3 @ a3*, c4 = W4 @ a4*
  matvec2_kernel<64,128> <<<16, 256, 0, stream>>>(W3, a3s, a3d, c3s, c3d);
  matvec2_kernel<128,256><<<32, 256, 0, stream>>>(W4, a4s, a4d, c4s, c4d);

  const int NWG  = (N_NODES + 3) / 4;          // agg3: 4 waves (nodes) per block
  const int G128 = (N_NODES + 127) / 128;      // gemm2 C=128 (TM=128)
  const int G64  = (N_NODES + 63) / 64;        // gemm2 C=256 (TM=64)

  // ---- layer 1: x(256) -> h1(128), relu after agg
  gemm2_kernel<256,128,true,false><<<G128, 256, 0, stream>>>(x, W1, bufPre, a1s, a1d, asb, adb, N_NODES);
  agg3_kernel<128,true><<<NWG, 256, 0, stream>>>(bufPre, asb, adb, rowptr, col, bufA, N_NODES);

  // ---- layer 2: h1(128) -> h2(128)
  gemm2_kernel<128,128,true,false><<<G128, 256, 0, stream>>>(bufA, W2, bufPre, a2s, a2d, asb, adb, N_NODES);
  agg3_kernel<128,false><<<NWG, 256, 0, stream>>>(bufPre, asb, adb, rowptr, col, bufB, N_NODES);

  // ---- mu / logvar / z  (fused [Wmu|Wlv] GEMM, then elementwise + fused z.c3 rowdot)
  combine_w_kernel<<<(128*128+255)/256, 256, 0, stream>>>(Wmu, Wlv, Wc);
  gemm2_kernel<128,128,false,false><<<G128, 256, 0, stream>>>(bufB, Wc, bufPre, nullptr, nullptr, nullptr, nullptr, N_NODES);
  z_kernel<<<(N_NODES*64)/256, 256, 0, stream>>>(bufPre, bmu, blv, eps, c3s, c3d,
                                                 out_mu, out_lv, out_z, asb, adb);

  // ---- layer 3 (commuted): agg z in 64-dim, then GEMM t3@W3 (+relu, +L4 score dots)
  agg3_kernel<64,false><<<NWG, 256, 0, stream>>>(out_z, asb, adb, rowptr, col, bufB, N_NODES);
  gemm2_kernel<64,128,true,true><<<G128, 256, 0, stream>>>(bufB, W3, bufA, c4s, c4d, asb, adb, N_NODES);

  // ---- layer 4 (commuted): agg h3 in 128-dim, then GEMM t4@W4 -> recon
  agg3_kernel<128,false><<<NWG, 256, 0, stream>>>(bufA, asb, adb, rowptr, col, bufPre, N_NODES);
  gemm2_kernel<128,256,false,false><<<G64, 256, 0, stream>>>(bufPre, W4, out_recon, nullptr, nullptr, nullptr, nullptr, N_NODES);
}